// Round 2
// baseline (158.848 us; speedup 1.0000x reference)
//
#include <hip/hip_runtime.h>
#include <stdint.h>

// Problem constants (B=8, T=2048, D=256, K=8192)
#define M_TOK 16384
#define DIM   256
#define KCB   8192
#define NGRP  8                    // N-groups (blocks in y)
#define GRP   1024                 // codes per group
#define NCHK  16                   // 16B fp8 k-chunks per row (256*1B/16B)
#define NT    16                   // 64-code tiles per group
#define SHIFT 512.0f               // positivity shift for score packing
#define INV_N (1.0f / 4194304.0f)  // 1/(B*T*D)
#define SC1   0x7F7F7F7F           // E8M0 scale bytes = 2^0 (op_sel-proof)

typedef __attribute__((ext_vector_type(4))) float f32x4;
typedef __attribute__((ext_vector_type(8))) int   i32x8;

// Async global->LDS DMA, 16 B/lane; LDS dest = wave-uniform base + lane*16.
static __device__ __forceinline__ void lds_cp16(const void* g, void* l) {
    __builtin_amdgcn_global_load_lds(
        (const __attribute__((address_space(1))) void*)g,
        (__attribute__((address_space(3))) void*)l, 16, 0, 0);
}

// pack 4 floats -> 4 fp8 e4m3 bytes (one dword)
static __device__ __forceinline__ int pk4(float4 f) {
    int o = __builtin_amdgcn_cvt_pk_fp8_f32(f.x, f.y, 0, false);
    o     = __builtin_amdgcn_cvt_pk_fp8_f32(f.z, f.w, o, true);
    return o;
}

// ---------------------------------------------------------------- kernel 1
// Codebook prep: cbt[chunk][code][16B] = fp8 of -c, k-chunk-major; chalf =
// 0.5||c||^2 + SHIFT. R13: 32 codes/block, grid 256 (was 128 = half the CUs
// idle). (wave w, half sub) handles chunks {4w+2sub, 4w+2sub+1}; lane&31 = code.
__global__ void k_prep(const float* __restrict__ cb,
                       unsigned char* __restrict__ cbt,
                       float* __restrict__ chalf) {
    __shared__ float part[8][32];
    const int w    = threadIdx.x >> 6;
    const int l    = threadIdx.x & 63;
    const int code = l & 31;
    const int sub  = l >> 5;
    const int grp8 = w * 2 + sub;          // 0..7, two chunks each
    const int c0   = blockIdx.x * 32;
    const float* row = cb + (size_t)(c0 + code) * DIM;
    float s = 0.0f;
    #pragma unroll
    for (int j = 0; j < 2; j++) {
        int ch = grp8 * 2 + j;
        const float* p = row + ch * 16;
        float4 a = *(const float4*)(p);
        float4 b = *(const float4*)(p + 4);
        float4 c = *(const float4*)(p + 8);
        float4 d = *(const float4*)(p + 12);
        s += a.x*a.x + a.y*a.y + a.z*a.z + a.w*a.w
           + b.x*b.x + b.y*b.y + b.z*b.z + b.w*b.w
           + c.x*c.x + c.y*c.y + c.z*c.z + c.w*c.w
           + d.x*d.x + d.y*d.y + d.z*d.z + d.w*d.w;
        float4 na = {-a.x, -a.y, -a.z, -a.w};
        float4 nb = {-b.x, -b.y, -b.z, -b.w};
        float4 nc = {-c.x, -c.y, -c.z, -c.w};
        float4 nd = {-d.x, -d.y, -d.z, -d.w};
        uint4 r;
        r.x = (unsigned)pk4(na); r.y = (unsigned)pk4(nb);
        r.z = (unsigned)pk4(nc); r.w = (unsigned)pk4(nd);
        *(uint4*)(cbt + ((size_t)ch * KCB + c0 + code) * 16) = r;
    }
    part[grp8][code] = s;
    __syncthreads();
    if (w == 0 && l < 32) {
        float t = 0.0f;
        #pragma unroll
        for (int i = 0; i < 8; i++) t += part[i][l];
        chalf[c0 + l] = 0.5f * t + SHIFT;
    }
}

// ---------------------------------------------------------------- kernel 2
// fp8-MX GEMM+argmin. R13 change: counted-vmcnt pipeline (T3/T4) instead of
// __syncthreads drain. Per tile: vmcnt(4) [next tile's DMAs stay in flight]
// -> s_barrier -> ks0 compute -> ks1 ds_reads -> lgkmcnt(0) -> s_barrier ->
// issue DMA(t+2) into freed buffer -> ks1 MFMA + fold. Prefetch depth 2
// phases, vmcnt never drains to 0 in-loop (m218: +38-73% on this lever).
// setprio(1) wraps MFMA clusters (T5; phase-split gives it role diversity).
__global__ __launch_bounds__(256, 4) void k_gemm_argmin(
    const float* __restrict__ xs,              // [M_TOK][DIM] fp32
    const unsigned char* __restrict__ cbt,     // [NCHK][KCB][16] fp8 of -c
    const float* __restrict__ chalf,           // [KCB] = 0.5||c||^2+SHIFT
    uint32_t* __restrict__ pkey)               // [M_TOK][NGRP]
{
    __shared__ __align__(16) unsigned char Bs[2][NCHK][64][16];   // 32 KB
    __shared__ float schalf[GRP];                                  // 4 KB

    const int tid  = threadIdx.x;
    const int w    = tid >> 6;
    const int l    = tid & 63;
    const int lrow = l & 15;
    const int quad = l >> 4;
    const int m0 = blockIdx.x * 128;
    const int g  = blockIdx.y;

    // staging source: wave w supplies chunks [4w,4w+4); lane = code in tile
    const unsigned char* bsrc = cbt + ((size_t)(w * 4) * KCB + g * GRP + l) * 16;

    // ---- A panel first (keeps vmcnt bookkeeping clean for the DMA pipeline):
    // 32 rows x 256 k, fp32 -> fp8 frags (2 rt x 2 ks x 8 dw)
    i32x8 afr[2][2];
    {
        const float* ap = xs + (size_t)(m0 + w * 32 + lrow) * DIM + quad * 32;
        #pragma unroll
        for (int rt = 0; rt < 2; rt++)
            #pragma unroll
            for (int ks = 0; ks < 2; ks++) {
                const float* p = ap + rt * 16 * DIM + ks * 128;
                union { int d[8]; i32x8 v; } aa;
                #pragma unroll
                for (int d = 0; d < 8; d++)
                    aa.d[d] = pk4(*(const float4*)(p + d * 4));
                afr[rt][ks] = aa.v;
            }
    }

    // schalf into LDS (global load completes before DMAs are issued below)
    *(float4*)&schalf[tid * 4] = ((const float4*)(chalf + g * GRP))[tid];
    asm volatile("s_waitcnt lgkmcnt(0)" ::: "memory");  // ds_write visible pre-barrier

    // ---- DMA prologue: tiles 0 and 1 (8 vmem ops in flight per wave)
    #pragma unroll
    for (int j = 0; j < 4; j++)
        lds_cp16(bsrc + ((size_t)j * KCB + 0 * 64) * 16, &Bs[0][w * 4 + j][0][0]);
    #pragma unroll
    for (int j = 0; j < 4; j++)
        lds_cp16(bsrc + ((size_t)j * KCB + 1 * 64) * 16, &Bs[1][w * 4 + j][0][0]);

    uint32_t best[2][4];
    #pragma unroll
    for (int rt = 0; rt < 2; rt++)
        #pragma unroll
        for (int rg = 0; rg < 4; rg++) best[rt][rg] = 0xFFFFFFFFu;

    #pragma unroll 1
    for (int t = 0; t < NT; t++) {
        const int cur = t & 1;
        // my DMA(t) done; DMA(t+1)'s 4 ops may stay in flight (never drain to
        // 0 mid-loop). Last tile has nothing behind it -> full wait.
        if (t == NT - 1) asm volatile("s_waitcnt vmcnt(0)" ::: "memory");
        else             asm volatile("s_waitcnt vmcnt(4)" ::: "memory");
        __builtin_amdgcn_s_barrier();          // collective: all waves' DMA(t) landed
        __builtin_amdgcn_sched_barrier(0);     // no ds_read hoists above barrier

        // acc init from schalf
        f32x4 acc[2][4];
        #pragma unroll
        for (int ct = 0; ct < 4; ct++) {
            float cs = schalf[t * 64 + ct * 16 + lrow];
            #pragma unroll
            for (int rt = 0; rt < 2; rt++) {
                f32x4 c4 = {cs, cs, cs, cs};
                acc[rt][ct] = c4;
            }
        }

        // ---- ks=0: LDS reads + MFMA
        {
            const int ch = quad * 2;
            i32x8 bfr[4];
            #pragma unroll
            for (int ct = 0; ct < 4; ct++) {
                union { uint4 q[2]; i32x8 v; } bb;
                bb.q[0] = *(const uint4*)&Bs[cur][ch][ct * 16 + lrow][0];
                bb.q[1] = *(const uint4*)&Bs[cur][ch + 1][ct * 16 + lrow][0];
                bfr[ct] = bb.v;
            }
            __builtin_amdgcn_s_setprio(1);
            #pragma unroll
            for (int rt = 0; rt < 2; rt++)
                #pragma unroll
                for (int ct = 0; ct < 4; ct++)
                    acc[rt][ct] = __builtin_amdgcn_mfma_scale_f32_16x16x128_f8f6f4(
                        afr[rt][0], bfr[ct], acc[rt][ct],
                        0, 0, 0, SC1, 0, SC1);
            __builtin_amdgcn_s_setprio(0);
        }

        // ---- ks=1: LDS reads, then free the buffer collectively
        i32x8 bfr1[4];
        {
            const int ch = 8 + quad * 2;
            #pragma unroll
            for (int ct = 0; ct < 4; ct++) {
                union { uint4 q[2]; i32x8 v; } bb;
                bb.q[0] = *(const uint4*)&Bs[cur][ch][ct * 16 + lrow][0];
                bb.q[1] = *(const uint4*)&Bs[cur][ch + 1][ct * 16 + lrow][0];
                bfr1[ct] = bb.v;
            }
        }
        asm volatile("s_waitcnt lgkmcnt(0)" ::: "memory");  // my Bs[cur] reads done
        __builtin_amdgcn_sched_barrier(0);                  // rule #18 pin
        __builtin_amdgcn_s_barrier();          // ALL waves done reading Bs[cur]
        __builtin_amdgcn_sched_barrier(0);     // DMA issue must not hoist above

        if (t < NT - 2) {                      // refill freed buffer with tile t+2
            #pragma unroll
            for (int j = 0; j < 4; j++)
                lds_cp16(bsrc + ((size_t)j * KCB + (t + 2) * 64) * 16,
                         &Bs[cur][w * 4 + j][0][0]);
        }

        __builtin_amdgcn_s_setprio(1);
        #pragma unroll
        for (int rt = 0; rt < 2; rt++)
            #pragma unroll
            for (int ct = 0; ct < 4; ct++)
                acc[rt][ct] = __builtin_amdgcn_mfma_scale_f32_16x16x128_f8f6f4(
                    afr[rt][1], bfr1[ct], acc[rt][ct],
                    0, 0, 0, SC1, 0, SC1);
        __builtin_amdgcn_s_setprio(0);

        // fold scores into packed keys: (score_bits & ~1023) | group-local id
        #pragma unroll
        for (int ct = 0; ct < 4; ct++) {
            uint32_t idl = (uint32_t)(t * 64 + ct * 16 + lrow);
            #pragma unroll
            for (int rt = 0; rt < 2; rt++)
                #pragma unroll
                for (int rg = 0; rg < 4; rg++) {
                    uint32_t key =
                        (__float_as_uint(acc[rt][ct][rg]) & 0xFFFFFC00u) | idl;
                    if (key < best[rt][rg]) best[rt][rg] = key;
                }
        }
    }

    // min across the 16 lanes of each quad group (same rows, different codes)
    #pragma unroll
    for (int off = 1; off < 16; off <<= 1)
        #pragma unroll
        for (int rt = 0; rt < 2; rt++)
            #pragma unroll
            for (int rg = 0; rg < 4; rg++) {
                uint32_t o = __shfl_xor(best[rt][rg], off);
                if (o < best[rt][rg]) best[rt][rg] = o;
            }
    if (lrow == 0) {
        #pragma unroll
        for (int rt = 0; rt < 2; rt++)
            #pragma unroll
            for (int rg = 0; rg < 4; rg++)
                pkey[(size_t)(m0 + w * 32 + rt * 16 + quad * 4 + rg) * NGRP + g]
                    = best[rt][rg];
    }
}

// ---------------------------------------------------------------- kernel 3
// Per row: min over 8 group keys -> final code; exact fp32 ||x-c||^2;
// per-block LDS reduce -> partial[blockIdx]. No global atomics/fences.
__global__ void k_finalize(const uint32_t* __restrict__ pkey,
                           const float4* __restrict__ xs4,
                           const float4* __restrict__ cb4,
                           float* __restrict__ partial) {
    __shared__ float sblk[4];
    int w   = threadIdx.x >> 6;
    int row = blockIdx.x * 4 + w;
    int l   = threadIdx.x & 63;
    uint32_t k = 0xFFFFFFFFu;
    int g = 0;
    if (l < 8) { k = pkey[(size_t)row * NGRP + l]; g = l; }
    #pragma unroll
    for (int off = 1; off < 8; off <<= 1) {
        uint32_t ok = __shfl_xor(k, off);
        int      og = __shfl_xor(g, off);
        if (ok < k) { k = ok; g = og; }
    }
    k = __shfl(k, 0);
    g = __shfl(g, 0);
    int code = g * GRP + (int)(k & 1023u);
    float4 x = xs4[(size_t)row * 64 + l];
    float4 c = cb4[(size_t)code * 64 + l];
    float dx = x.x - c.x, dy = x.y - c.y, dz = x.z - c.z, dw = x.w - c.w;
    float s = dx * dx + dy * dy + dz * dz + dw * dw;
    #pragma unroll
    for (int off = 32; off; off >>= 1) s += __shfl_xor(s, off);
    if (l == 0) sblk[w] = s;
    __syncthreads();
    if (threadIdx.x == 0)
        partial[blockIdx.x] = sblk[0] + sblk[1] + sblk[2] + sblk[3];
}

// ---------------------------------------------------------------- kernel 4
__global__ void k_write(const float* __restrict__ partial,
                        float* __restrict__ out) {
    __shared__ float swv[16];
    int tid = threadIdx.x;                    // 1024 threads = 16 waves
    float s = partial[tid] + partial[tid + 1024] +
              partial[tid + 2048] + partial[tid + 3072];
    #pragma unroll
    for (int off = 32; off; off >>= 1) s += __shfl_xor(s, off);
    if ((tid & 63) == 0) swv[tid >> 6] = s;
    __syncthreads();
    if (tid == 0) {
        float t = 0.0f;
        #pragma unroll
        for (int i = 0; i < 16; i++) t += swv[i];
        float commit = t * INV_N;
        out[0] = 0.25f * commit;   // loss
        out[1] = commit;           // commit_loss
    }
}

extern "C" void kernel_launch(void* const* d_in, const int* in_sizes, int n_in,
                              void* d_out, int out_size, void* d_ws, size_t ws_size,
                              hipStream_t stream) {
    const float* xs = (const float*)d_in[0];
    // d_in[1] = ilens (int64, all == T) -> slice is a no-op, unused
    const float* cb = (const float*)d_in[2];

    char* ws = (char*)d_ws;
    unsigned char* cbt     = (unsigned char*)(ws + 256);            // 2 MiB
    float*         chalf   = (float*)(ws + 256 + 2097152);          // 32 KiB
    uint32_t*      pkey    = (uint32_t*)(ws + 256 + 2129920);       // 512 KiB
    float*         partial = (float*)(ws + 256 + 2654208);          // 16 KiB

    k_prep<<<256, 256, 0, stream>>>(cb, cbt, chalf);
    dim3 g(M_TOK / 128, NGRP);
    k_gemm_argmin<<<g, 256, 0, stream>>>(xs, cbt, chalf, pkey);
    k_finalize<<<4096, 256, 0, stream>>>(pkey, (const float4*)xs,
                                         (const float4*)cb, partial);
    k_write<<<1, 1024, 0, stream>>>(partial, (float*)d_out);
}

// Round 3
// 118.826 us; speedup vs baseline: 1.3368x; 1.3368x over previous
//
#include <hip/hip_runtime.h>
#include <stdint.h>

// Problem constants (B=8, T=2048, D=256, K=8192)
#define M_TOK 16384
#define DIM   256
#define KCB   8192
#define NGRP  8                    // N-groups (blocks in y)
#define GRP   1024                 // codes per group
#define NCHK  16                   // 16B fp8 k-chunks per row (256*1B/16B)
#define NT    16                   // 64-code tiles per group
#define SHIFT 512.0f               // positivity shift for score packing
#define INV_N (1.0f / 4194304.0f)  // 1/(B*T*D)
#define SC1   0x7F7F7F7F           // E8M0 scale bytes = 2^0 (op_sel-proof)

typedef __attribute__((ext_vector_type(4))) float f32x4;
typedef __attribute__((ext_vector_type(8))) int   i32x8;

// Async global->LDS DMA, 16 B/lane; LDS dest = wave-uniform base + lane*16.
static __device__ __forceinline__ void lds_cp16(const void* g, void* l) {
    __builtin_amdgcn_global_load_lds(
        (const __attribute__((address_space(1))) void*)g,
        (__attribute__((address_space(3))) void*)l, 16, 0, 0);
}

// pack 4 floats -> 4 fp8 e4m3 bytes (one dword)
static __device__ __forceinline__ int pk4(float4 f) {
    int o = __builtin_amdgcn_cvt_pk_fp8_f32(f.x, f.y, 0, false);
    o     = __builtin_amdgcn_cvt_pk_fp8_f32(f.z, f.w, o, true);
    return o;
}

// ---------------------------------------------------------------- kernel 1
// Codebook prep: cbt[chunk][code][16B] = fp8 of -c, k-chunk-major; chalf =
// 0.5||c||^2 + SHIFT. 32 codes/block, grid 256 (all CUs busy).
__global__ void k_prep(const float* __restrict__ cb,
                       unsigned char* __restrict__ cbt,
                       float* __restrict__ chalf) {
    __shared__ float part[8][32];
    const int w    = threadIdx.x >> 6;
    const int l    = threadIdx.x & 63;
    const int code = l & 31;
    const int sub  = l >> 5;
    const int grp8 = w * 2 + sub;          // 0..7, two chunks each
    const int c0   = blockIdx.x * 32;
    const float* row = cb + (size_t)(c0 + code) * DIM;
    float s = 0.0f;
    #pragma unroll
    for (int j = 0; j < 2; j++) {
        int ch = grp8 * 2 + j;
        const float* p = row + ch * 16;
        float4 a = *(const float4*)(p);
        float4 b = *(const float4*)(p + 4);
        float4 c = *(const float4*)(p + 8);
        float4 d = *(const float4*)(p + 12);
        s += a.x*a.x + a.y*a.y + a.z*a.z + a.w*a.w
           + b.x*b.x + b.y*b.y + b.z*b.z + b.w*b.w
           + c.x*c.x + c.y*c.y + c.z*c.z + c.w*c.w
           + d.x*d.x + d.y*d.y + d.z*d.z + d.w*d.w;
        float4 na = {-a.x, -a.y, -a.z, -a.w};
        float4 nb = {-b.x, -b.y, -b.z, -b.w};
        float4 nc = {-c.x, -c.y, -c.z, -c.w};
        float4 nd = {-d.x, -d.y, -d.z, -d.w};
        uint4 r;
        r.x = (unsigned)pk4(na); r.y = (unsigned)pk4(nb);
        r.z = (unsigned)pk4(nc); r.w = (unsigned)pk4(nd);
        *(uint4*)(cbt + ((size_t)ch * KCB + c0 + code) * 16) = r;
    }
    part[grp8][code] = s;
    __syncthreads();
    if (w == 0 && l < 32) {
        float t = 0.0f;
        #pragma unroll
        for (int i = 0; i < 8; i++) t += part[i][l];
        chalf[c0 + l] = 0.5f * t + SHIFT;
    }
}

// fold one ct-pair of accumulators into packed keys.
// key = (score_bits & ~1023) | group-local id  ->  v_and_or_b32 + v_min_u32.
#define FOLD2(ACC, TT, CB)                                                   \
    do {                                                                     \
        _Pragma("unroll")                                                    \
        for (int _j = 0; _j < 2; _j++) {                                     \
            uint32_t _idl = (uint32_t)((TT) * 64 + ((CB) + _j) * 16 + lrow); \
            _Pragma("unroll")                                                \
            for (int _rt = 0; _rt < 2; _rt++)                                \
                _Pragma("unroll")                                            \
                for (int _rg = 0; _rg < 4; _rg++) {                          \
                    uint32_t _key =                                          \
                        (__float_as_uint(ACC[_rt][_j][_rg]) & 0xFFFFFC00u)   \
                        | _idl;                                              \
                    if (_key < best[_rt][_rg]) best[_rt][_rg] = _key;        \
                }                                                            \
        }                                                                    \
    } while (0)

// ---------------------------------------------------------------- kernel 2
// fp8-MX double-buffered GEMM+argmin. R14: anti-convoy restructure (R13's
// counted-vmcnt spilled 27MB to scratch; reverted to __syncthreads, whose
// vmcnt(0) drain is provably cheap here - DMA has a full phase of cover).
// R1 counters showed phase-serialized pipes (MFMA 27% + LDS 42% + VALU 34%
// ~= 100%). Fixes, all pure C++ reordering (bit-exact keys):
//  - fold of ct{0,1} placed under ks1-ct{2,3} MFMA shadow (independent ops)
//  - fold of ct{2,3} DEFERRED into next tile's MFMA phase (+16 VGPR only)
//  - acc init folded into first MFMA's C operand (kills 32 movs/tile)
//  - 2-op fold: and_or + min_u32
//  - pair-pipelined ds_reads: each read cluster hides under prior MFMAs
// Register peak ~120 < 128 cap (launch_bounds 256,4 -> 4 waves/SIMD).
__global__ __launch_bounds__(256, 4) void k_gemm_argmin(
    const float* __restrict__ xs,              // [M_TOK][DIM] fp32
    const unsigned char* __restrict__ cbt,     // [NCHK][KCB][16] fp8 of -c
    const float* __restrict__ chalf,           // [KCB] = 0.5||c||^2+SHIFT
    uint32_t* __restrict__ pkey)               // [M_TOK][NGRP]
{
    __shared__ __align__(16) unsigned char Bs[2][NCHK][64][16];   // 32 KB
    __shared__ float schalf[GRP];                                  // 4 KB

    const int tid  = threadIdx.x;
    const int w    = tid >> 6;
    const int l    = tid & 63;
    const int lrow = l & 15;
    const int quad = l >> 4;
    const int m0 = blockIdx.x * 128;
    const int g  = blockIdx.y;

    *(float4*)&schalf[tid * 4] = ((const float4*)(chalf + g * GRP))[tid];

    // staging: wave w supplies chunks [4w,4w+4); lane = code in tile
    const unsigned char* bsrc = cbt + ((size_t)(w * 4) * KCB + g * GRP + l) * 16;

    #pragma unroll
    for (int j = 0; j < 4; j++)
        lds_cp16(bsrc + (size_t)j * KCB * 16, &Bs[0][w * 4 + j][0][0]);

    // ---- A panel: 32 rows x 256 k, fp32 -> fp8 frags (2 rt x 2 ks x 8 dw)
    // (VALU-heavy; overlaps the tile-0 DMA above)
    i32x8 afr[2][2];
    {
        const float* ap = xs + (size_t)(m0 + w * 32 + lrow) * DIM + quad * 32;
        #pragma unroll
        for (int rt = 0; rt < 2; rt++)
            #pragma unroll
            for (int ks = 0; ks < 2; ks++) {
                const float* p = ap + rt * 16 * DIM + ks * 128;
                union { int d[8]; i32x8 v; } aa;
                #pragma unroll
                for (int d = 0; d < 8; d++)
                    aa.d[d] = pk4(*(const float4*)(p + d * 4));
                afr[rt][ks] = aa.v;
            }
    }

    uint32_t best[2][4];
    #pragma unroll
    for (int rt = 0; rt < 2; rt++)
        #pragma unroll
        for (int rg = 0; rg < 4; rg++) best[rt][rg] = 0xFFFFFFFFu;

    // deferred-fold carrier for ct{2,3}; FLT_MAX so iteration 0's dummy fold
    // only writes keys ~0x7F7FFCxx that any real key (~0x44xxxxxx) beats.
    f32x4 acc23[2][2];
    {
        const float fm = __uint_as_float(0x7F7FFFFFu);
        f32x4 fmv = {fm, fm, fm, fm};
        #pragma unroll
        for (int rt = 0; rt < 2; rt++)
            #pragma unroll
            for (int j = 0; j < 2; j++) acc23[rt][j] = fmv;
    }

    #pragma unroll 1
    for (int t = 0; t < NT; t++) {
        const int cur = t & 1;
        __syncthreads();   // drains DMA(t) issued one compute phase ago
        if (t < NT - 1) {  // prefetch t+1 AFTER the barrier
            #pragma unroll
            for (int j = 0; j < 4; j++)
                lds_cp16(bsrc + ((size_t)j * KCB + (t + 1) * 64) * 16,
                         &Bs[1 - cur][w * 4 + j][0][0]);
        }

        float cs[4];
        #pragma unroll
        for (int ct = 0; ct < 4; ct++) cs[ct] = schalf[t * 64 + ct * 16 + lrow];

        const int chA = quad * 2;        // ks0 chunk base for this lane
        const int chB = 8 + quad * 2;    // ks1 chunk base

        // ks0 reads: pair0 (ct0,1) then pair1 (ct2,3)
        i32x8 bA[2], bB[2];
        #pragma unroll
        for (int j = 0; j < 2; j++) {
            union { uint4 q[2]; i32x8 v; } bb;
            bb.q[0] = *(const uint4*)&Bs[cur][chA][j * 16 + lrow][0];
            bb.q[1] = *(const uint4*)&Bs[cur][chA + 1][j * 16 + lrow][0];
            bA[j] = bb.v;
        }
        #pragma unroll
        for (int j = 0; j < 2; j++) {
            union { uint4 q[2]; i32x8 v; } bb;
            bb.q[0] = *(const uint4*)&Bs[cur][chA][(2 + j) * 16 + lrow][0];
            bb.q[1] = *(const uint4*)&Bs[cur][chA + 1][(2 + j) * 16 + lrow][0];
            bB[j] = bb.v;
        }

        // mfma ks0 pair0 (C-init with cs splat; waits only pair0 reads)
        f32x4 acc01[2][2];
        #pragma unroll
        for (int j = 0; j < 2; j++) {
            f32x4 c4 = {cs[j], cs[j], cs[j], cs[j]};
            #pragma unroll
            for (int rt = 0; rt < 2; rt++)
                acc01[rt][j] = __builtin_amdgcn_mfma_scale_f32_16x16x128_f8f6f4(
                    afr[rt][0], bA[j], c4, 0, 0, 0, SC1, 0, SC1);
        }

        // deferred fold of PREVIOUS tile's ct{2,3} — independent VALU that
        // fills this tile's MFMA/ds_read shadows.
        FOLD2(acc23, t - 1, 2);

        // ks1 reads pair0 (reuse bA)
        #pragma unroll
        for (int j = 0; j < 2; j++) {
            union { uint4 q[2]; i32x8 v; } bb;
            bb.q[0] = *(const uint4*)&Bs[cur][chB][j * 16 + lrow][0];
            bb.q[1] = *(const uint4*)&Bs[cur][chB + 1][j * 16 + lrow][0];
            bA[j] = bb.v;
        }

        // mfma ks0 pair1 (C-init)
        #pragma unroll
        for (int j = 0; j < 2; j++) {
            f32x4 c4 = {cs[2 + j], cs[2 + j], cs[2 + j], cs[2 + j]};
            #pragma unroll
            for (int rt = 0; rt < 2; rt++)
                acc23[rt][j] = __builtin_amdgcn_mfma_scale_f32_16x16x128_f8f6f4(
                    afr[rt][0], bB[j], c4, 0, 0, 0, SC1, 0, SC1);
        }

        // ks1 reads pair1 (reuse bB)
        #pragma unroll
        for (int j = 0; j < 2; j++) {
            union { uint4 q[2]; i32x8 v; } bb;
            bb.q[0] = *(const uint4*)&Bs[cur][chB][(2 + j) * 16 + lrow][0];
            bb.q[1] = *(const uint4*)&Bs[cur][chB + 1][(2 + j) * 16 + lrow][0];
            bB[j] = bb.v;
        }

        // mfma ks1 pair0 -> acc01 final
        #pragma unroll
        for (int j = 0; j < 2; j++)
            #pragma unroll
            for (int rt = 0; rt < 2; rt++)
                acc01[rt][j] = __builtin_amdgcn_mfma_scale_f32_16x16x128_f8f6f4(
                    afr[rt][1], bA[j], acc01[rt][j], 0, 0, 0, SC1, 0, SC1);

        // mfma ks1 pair1 -> acc23 final (fold deferred to next tile)
        #pragma unroll
        for (int j = 0; j < 2; j++)
            #pragma unroll
            for (int rt = 0; rt < 2; rt++)
                acc23[rt][j] = __builtin_amdgcn_mfma_scale_f32_16x16x128_f8f6f4(
                    afr[rt][1], bB[j], acc23[rt][j], 0, 0, 0, SC1, 0, SC1);

        // fold pair0 now — overlaps the ks1-pair1 MFMA shadow above
        FOLD2(acc01, t, 0);
    }
    // epilogue: fold the last tile's deferred pair
    FOLD2(acc23, NT - 1, 2);

    // min across the 16 lanes of each quad group (same rows, different codes)
    #pragma unroll
    for (int off = 1; off < 16; off <<= 1)
        #pragma unroll
        for (int rt = 0; rt < 2; rt++)
            #pragma unroll
            for (int rg = 0; rg < 4; rg++) {
                uint32_t o = __shfl_xor(best[rt][rg], off);
                if (o < best[rt][rg]) best[rt][rg] = o;
            }
    if (lrow == 0) {
        #pragma unroll
        for (int rt = 0; rt < 2; rt++)
            #pragma unroll
            for (int rg = 0; rg < 4; rg++)
                pkey[(size_t)(m0 + w * 32 + rt * 16 + quad * 4 + rg) * NGRP + g]
                    = best[rt][rg];
    }
}

// ---------------------------------------------------------------- kernel 3
// Per row: min over 8 group keys -> final code; exact fp32 ||x-c||^2;
// per-block LDS reduce -> partial[blockIdx]. No global atomics/fences.
__global__ void k_finalize(const uint32_t* __restrict__ pkey,
                           const float4* __restrict__ xs4,
                           const float4* __restrict__ cb4,
                           float* __restrict__ partial) {
    __shared__ float sblk[4];
    int w   = threadIdx.x >> 6;
    int row = blockIdx.x * 4 + w;
    int l   = threadIdx.x & 63;
    uint32_t k = 0xFFFFFFFFu;
    int g = 0;
    if (l < 8) { k = pkey[(size_t)row * NGRP + l]; g = l; }
    #pragma unroll
    for (int off = 1; off < 8; off <<= 1) {
        uint32_t ok = __shfl_xor(k, off);
        int      og = __shfl_xor(g, off);
        if (ok < k) { k = ok; g = og; }
    }
    k = __shfl(k, 0);
    g = __shfl(g, 0);
    int code = g * GRP + (int)(k & 1023u);
    float4 x = xs4[(size_t)row * 64 + l];
    float4 c = cb4[(size_t)code * 64 + l];
    float dx = x.x - c.x, dy = x.y - c.y, dz = x.z - c.z, dw = x.w - c.w;
    float s = dx * dx + dy * dy + dz * dz + dw * dw;
    #pragma unroll
    for (int off = 32; off; off >>= 1) s += __shfl_xor(s, off);
    if (l == 0) sblk[w] = s;
    __syncthreads();
    if (threadIdx.x == 0)
        partial[blockIdx.x] = sblk[0] + sblk[1] + sblk[2] + sblk[3];
}

// ---------------------------------------------------------------- kernel 4
__global__ void k_write(const float* __restrict__ partial,
                        float* __restrict__ out) {
    __shared__ float swv[16];
    int tid = threadIdx.x;                    // 1024 threads = 16 waves
    float s = partial[tid] + partial[tid + 1024] +
              partial[tid + 2048] + partial[tid + 3072];
    #pragma unroll
    for (int off = 32; off; off >>= 1) s += __shfl_xor(s, off);
    if ((tid & 63) == 0) swv[tid >> 6] = s;
    __syncthreads();
    if (tid == 0) {
        float t = 0.0f;
        #pragma unroll
        for (int i = 0; i < 16; i++) t += swv[i];
        float commit = t * INV_N;
        out[0] = 0.25f * commit;   // loss
        out[1] = commit;           // commit_loss
    }
}

extern "C" void kernel_launch(void* const* d_in, const int* in_sizes, int n_in,
                              void* d_out, int out_size, void* d_ws, size_t ws_size,
                              hipStream_t stream) {
    const float* xs = (const float*)d_in[0];
    // d_in[1] = ilens (int64, all == T) -> slice is a no-op, unused
    const float* cb = (const float*)d_in[2];

    char* ws = (char*)d_ws;
    unsigned char* cbt     = (unsigned char*)(ws + 256);            // 2 MiB
    float*         chalf   = (float*)(ws + 256 + 2097152);          // 32 KiB
    uint32_t*      pkey    = (uint32_t*)(ws + 256 + 2129920);       // 512 KiB
    float*         partial = (float*)(ws + 256 + 2654208);          // 16 KiB

    k_prep<<<256, 256, 0, stream>>>(cb, cbt, chalf);
    dim3 g(M_TOK / 128, NGRP);
    k_gemm_argmin<<<g, 256, 0, stream>>>(xs, cbt, chalf, pkey);
    k_finalize<<<4096, 256, 0, stream>>>(pkey, (const float4*)xs,
                                         (const float4*)cb, partial);
    k_write<<<1, 1024, 0, stream>>>(partial, (float*)d_out);
}